// Round 2
// baseline (1525.572 us; speedup 1.0000x reference)
//
#include <hip/hip_runtime.h>
#include <math.h>

#define HH 1080
#define WW 1920
#define RAD 5
#define TX 32
#define TY 32
#define RPT 4
#define BDY 8
#define LR (TY + 2*RAD)   // 42
#define LC (TX + 2*RAD)   // 42

__device__ __forceinline__ float fast_rcp(float x) {
#if __has_builtin(__builtin_amdgcn_rcpf)
    return __builtin_amdgcn_rcpf(x);
#else
    return 1.0f / x;
#endif
}
__device__ __forceinline__ float fast_rsq(float x) {
#if __has_builtin(__builtin_amdgcn_rsqf)
    return __builtin_amdgcn_rsqf(x);
#else
    return rsqrtf(x);
#endif
}
__device__ __forceinline__ float fast_log2(float x) {
#if __has_builtin(__builtin_amdgcn_logf)
    return __builtin_amdgcn_logf(x);
#else
    return __log2f(x);
#endif
}
__device__ __forceinline__ float fast_exp2(float x) {
#if __has_builtin(__builtin_amdgcn_exp2f)
    return __builtin_amdgcn_exp2f(x);
#else
    return exp2f(x);
#endif
}

// constexpr sqrt (Newton) so the per-tap 1/sqrt(d2) folds to a literal
constexpr double csqrt_(double x) {
    double g = (x < 1.0) ? 1.0 : x;
    for (int i = 0; i < 80; ++i) g = 0.5 * (g + x / g);
    return g;  // csqrt_(0) -> ~2^-80, harmless (clamped by fminf below)
}
struct Tbl {
    float cxy[51];   // -d2/(2*sigma^2) * log2(e) = -d2 * 0.18033688
    float rsd[51];   // log2(e) / sqrt(d2)   (folded log2e for the depth term)
    constexpr Tbl() : cxy{}, rsd{} {
        for (int i = 0; i < 51; ++i) {
            cxy[i] = (float)(-(double)i * 0.18033688011112042);
            rsd[i] = (float)(1.4426950408889634 / csqrt_((double)i));
        }
    }
};

// Weight: w = exp(-d2/8) * clip(dot,0,1)^128 * exp(-|tz-z| / max(dz*sqrt(d2), 1e-4))
// Fused:  w = exp2( CXY[d2] + 128*log2(max(dot,0)) - |tz-z| * min(rcp(dz)*RSD[d2], 1e4*log2e) )
// using 1/max(a,eps) == min(1/a, 1/eps). Center tap: dz_tap==z -> term 0; dot==1 -> log2=0 -> w=1.
// Zero-padded halo: normals 0 -> dot 0 -> log2(0)=-inf -> w=0 == reference mask t_m.

__global__ __launch_bounds__(TX*BDY, 4)
void denoise_kernel(const float* __restrict__ in, float* __restrict__ out) {
    __shared__ float4 sA[LR][LC];   // c0,c1,c2,n0   28224 B
    __shared__ float2 sN[LR][LC];   // n1,n2         14112 B
    __shared__ float  sZ[LR][LC];   // z              7056 B -> 49392 B total, 3 blocks/CU

    const int tx = threadIdx.x;
    const int ty = threadIdx.y;
    const int tid = ty * TX + tx;
    const int x0 = blockIdx.x * TX;
    const int y0 = blockIdx.y * TY;

    // ---- stage tile + halo, normalizing normals on the fly ----
    #pragma unroll
    for (int i = 0; i < (LR * LC + TX * BDY - 1) / (TX * BDY); ++i) {
        int idx = tid + i * (TX * BDY);
        if (idx < LR * LC) {
            int r = idx / LC, c = idx % LC;
            int gx = x0 + c - RAD;
            int gy = y0 + r - RAD;
            float4 a = make_float4(0.f, 0.f, 0.f, 0.f);
            float4 b = make_float4(0.f, 0.f, 0.f, 0.f);
            if ((unsigned)gx < (unsigned)WW && (unsigned)gy < (unsigned)HH) {
                const float4* p = reinterpret_cast<const float4*>(in + ((size_t)gy * WW + gx) * 8);
                a = p[0];
                b = p[1];
            }
            float nn = a.w * a.w + b.x * b.x + b.y * b.y;
            float s = fast_rsq(fmaxf(nn, 1e-20f));
            sA[r][c] = make_float4(a.x, a.y, a.z, a.w * s);
            sN[r][c] = make_float2(b.x * s, b.y * s);
            sZ[r][c] = b.z;
        }
    }
    __syncthreads();

    // ---- per-thread centers: 4 vertically adjacent outputs ----
    float cn0[RPT], cn1[RPT], cn2[RPT], cz[RPT], rdz[RPT];
    #pragma unroll
    for (int o = 0; o < RPT; ++o) {
        int rr = ty * RPT + RAD + o, cc = tx + RAD;
        float4 A = sA[rr][cc];
        float2 N = sN[rr][cc];
        cn0[o] = A.w; cn1[o] = N.x; cn2[o] = N.y; cz[o] = sZ[rr][cc];
        int gy = y0 + ty * RPT + o;
        float dzv = 1.0f;
        if (gy < HH) dzv = in[(((size_t)gy * WW) + (x0 + tx)) * 8 + 7];
        rdz[o] = fast_rcp(dzv);
    }

    float accx[RPT] = {0.f, 0.f, 0.f, 0.f};
    float accy[RPT] = {0.f, 0.f, 0.f, 0.f};
    float accz[RPT] = {0.f, 0.f, 0.f, 0.f};
    float accw[RPT] = {0.f, 0.f, 0.f, 0.f};

    constexpr Tbl TBL{};

    // ---- fully unrolled tap loop: dy compile-time -> dead bodies removed,
    //      sqrt/d2 constants folded; each tap read once, reused by 4 outputs ----
    #pragma unroll
    for (int r = 0; r < 2 * RAD + RPT; ++r) {
        #pragma unroll
        for (int dx = 0; dx < 2 * RAD + 1; ++dx) {
            float4 A  = sA[ty * RPT + r][tx + dx];
            float2 N  = sN[ty * RPT + r][tx + dx];
            float  tz = sZ[ty * RPT + r][tx + dx];
            #pragma unroll
            for (int o = 0; o < RPT; ++o) {
                const int dy = r - RAD - o;
                if (dy >= -RAD && dy <= RAD) {
                    const int d2i = dy * dy + (dx - RAD) * (dx - RAD);
                    const float cxy = TBL.cxy[d2i];
                    const float rsl = TBL.rsd[d2i];
                    float dot = fmaf(A.w, cn0[o], fmaf(N.x, cn1[o], N.y * cn2[o]));
                    float lg  = fast_log2(fmaxf(dot, 0.0f));
                    float eb  = fmaf(lg, 128.0f, cxy);
                    float tm  = fminf(rdz[o] * rsl, 14426.950408889634f);
                    float zd  = tz - cz[o];
                    float e2  = fmaf(-fabsf(zd), tm, eb);
                    float w   = fast_exp2(e2);
                    accx[o] = fmaf(A.x, w, accx[o]);
                    accy[o] = fmaf(A.y, w, accy[o]);
                    accz[o] = fmaf(A.z, w, accz[o]);
                    accw[o] += w;
                }
            }
        }
    }

    // ---- epilogue ----
    const int xo = x0 + tx;
    #pragma unroll
    for (int o = 0; o < RPT; ++o) {
        int y = y0 + ty * RPT + o;
        if (y < HH) {
            float inv = fast_rcp(accw[o]);
            size_t base = ((size_t)y * WW + xo) * 3;
            out[base + 0] = accx[o] * inv;
            out[base + 1] = accy[o] * inv;
            out[base + 2] = accz[o] * inv;
        }
    }
}

extern "C" void kernel_launch(void* const* d_in, const int* in_sizes, int n_in,
                              void* d_out, int out_size, void* d_ws, size_t ws_size,
                              hipStream_t stream) {
    const float* in = (const float*)d_in[0];
    float* out = (float*)d_out;
    dim3 grid((WW + TX - 1) / TX, (HH + TY - 1) / TY);   // 60 x 34
    dim3 block(TX, BDY);                                  // 256 threads
    hipLaunchKernelGGL(denoise_kernel, grid, block, 0, stream, in, out);
}

// Round 3
// 133.724 us; speedup vs baseline: 11.4084x; 11.4084x over previous
//
#include <hip/hip_runtime.h>
#include <math.h>

#define HH 1080
#define WW 1920
#define RAD 5
#define TX 32
#define TY 32
#define RPT 4
#define BDY 8
#define LR (TY + 2*RAD)   // 42
#define LC (TX + 2*RAD)   // 42

__device__ __forceinline__ float fast_rcp(float x) {
#if __has_builtin(__builtin_amdgcn_rcpf)
    return __builtin_amdgcn_rcpf(x);
#else
    return 1.0f / x;
#endif
}
__device__ __forceinline__ float fast_rsq(float x) {
#if __has_builtin(__builtin_amdgcn_rsqf)
    return __builtin_amdgcn_rsqf(x);
#else
    return rsqrtf(x);
#endif
}
__device__ __forceinline__ float fast_log2(float x) {
#if __has_builtin(__builtin_amdgcn_logf)
    return __builtin_amdgcn_logf(x);
#else
    return __log2f(x);
#endif
}
__device__ __forceinline__ float fast_exp2(float x) {
#if __has_builtin(__builtin_amdgcn_exp2f)
    return __builtin_amdgcn_exp2f(x);
#else
    return exp2f(x);
#endif
}

// Weight: w = exp(-d2/8) * clip(dot,0,1)^128 * exp(-|tz-z| / max(dz*sqrt(d2), 1e-4))
// Fused:  w = exp2( -c*d2 + 128*log2(max(dot,0)) - |tz-z| * min(rdz*rsqrt(d2), 1e4*log2e) )
//   where c = 0.18033688 (= log2e/8), rdz = log2e * rcp(dz)  (hoisted per center),
//   using 1/max(a,eps) == min(1/a, 1/eps) for a>=0.
// Center tap (d2=0): rsqrt(0)=inf -> tm clamps to BIG, zd==0 -> fma(-0,BIG,eb)=eb; dot==1 -> w=1. Exact.
// Zero-padded halo: normals 0 -> dot 0 -> log2(0)=-inf -> w=0, reproducing reference mask t_m.
// (Numerics of this exact fusion validated in R2: absmax 3.9e-3 vs threshold 2e-2.)

__global__ __launch_bounds__(TX*BDY, 3)
void denoise_kernel(const float* __restrict__ in, float* __restrict__ out) {
    __shared__ float4 sA[LR][LC];   // c0,c1,c2,n0   28224 B
    __shared__ float2 sN[LR][LC];   // n1,n2         14112 B
    __shared__ float  sZ[LR][LC];   // z              7056 B  -> 49392 B total -> 3 blocks/CU

    const int tx = threadIdx.x;
    const int ty = threadIdx.y;
    const int tid = ty * TX + tx;
    const int x0 = blockIdx.x * TX;
    const int y0 = blockIdx.y * TY;

    // ---- stage tile + halo, normalizing normals on the fly ----
    #pragma unroll
    for (int i = 0; i < (LR * LC + TX * BDY - 1) / (TX * BDY); ++i) {
        int idx = tid + i * (TX * BDY);
        if (idx < LR * LC) {
            int r = idx / LC, c = idx % LC;
            int gx = x0 + c - RAD;
            int gy = y0 + r - RAD;
            float4 a = make_float4(0.f, 0.f, 0.f, 0.f);
            float4 b = make_float4(0.f, 0.f, 0.f, 0.f);
            if ((unsigned)gx < (unsigned)WW && (unsigned)gy < (unsigned)HH) {
                const float4* p = reinterpret_cast<const float4*>(in + ((size_t)gy * WW + gx) * 8);
                a = p[0];
                b = p[1];
            }
            float nn = a.w * a.w + b.x * b.x + b.y * b.y;
            float s = fast_rsq(fmaxf(nn, 1e-20f));
            sA[r][c] = make_float4(a.x, a.y, a.z, a.w * s);
            sN[r][c] = make_float2(b.x * s, b.y * s);
            sZ[r][c] = b.z;
        }
    }
    __syncthreads();

    // ---- per-thread centers: 4 vertically adjacent outputs ----
    float cn0[RPT], cn1[RPT], cn2[RPT], cz[RPT], rdz[RPT];
    #pragma unroll
    for (int o = 0; o < RPT; ++o) {
        int rr = ty * RPT + RAD + o, cc = tx + RAD;
        float4 A = sA[rr][cc];
        float2 N = sN[rr][cc];
        cn0[o] = A.w; cn1[o] = N.x; cn2[o] = N.y; cz[o] = sZ[rr][cc];
        int gy = y0 + ty * RPT + o;
        float dzv = 1.0f;
        if (gy < HH) dzv = in[(((size_t)gy * WW) + (x0 + tx)) * 8 + 7];
        rdz[o] = 1.4426950408889634f * fast_rcp(dzv);   // log2e folded in
    }

    float accx[RPT] = {0.f, 0.f, 0.f, 0.f};
    float accy[RPT] = {0.f, 0.f, 0.f, 0.f};
    float accz[RPT] = {0.f, 0.f, 0.f, 0.f};
    float accw[RPT] = {0.f, 0.f, 0.f, 0.f};

    // ---- main tap loop: RUNTIME r loop (14 iters) -- do NOT unroll (R2 spill lesson);
    //      each tap read from LDS once, reused by up to 4 outputs ----
    for (int r = 0; r < 2 * RAD + RPT; ++r) {
        float dy2f[RPT], pcy[RPT];
        bool  val[RPT];
        #pragma unroll
        for (int o = 0; o < RPT; ++o) {
            int dy = r - RAD - o;
            val[o] = (dy >= -RAD) && (dy <= RAD);
            float fd = (float)dy;
            dy2f[o] = fd * fd;
            pcy[o]  = dy2f[o] * -0.18033688011112042f;  // -dy^2 * log2e/8
        }
        #pragma unroll
        for (int dx = 0; dx < 2 * RAD + 1; ++dx) {
            float4 A  = sA[ty * RPT + r][tx + dx];
            float2 N  = sN[ty * RPT + r][tx + dx];
            float  tz = sZ[ty * RPT + r][tx + dx];
            const float dx2f = (float)((dx - RAD) * (dx - RAD));
            const float pcx  = dx2f * -0.18033688011112042f;
            #pragma unroll
            for (int o = 0; o < RPT; ++o) {
                if (val[o]) {
                    float d2  = dy2f[o] + dx2f;
                    float cxy = pcy[o] + pcx;
                    float rsq = fast_rsq(d2);                        // inf at center, clamped below
                    float dot = fmaf(A.w, cn0[o], fmaf(N.x, cn1[o], N.y * cn2[o]));
                    float lg  = fast_log2(fmaxf(dot, 0.0f));         // -inf at 0 -> w=0
                    float eb  = fmaf(lg, 128.0f, cxy);
                    float tm  = fminf(rdz[o] * rsq, 14426.950408889634f);  // 1e4*log2e
                    float zd  = tz - cz[o];
                    float e2  = fmaf(-fabsf(zd), tm, eb);
                    float w   = fast_exp2(e2);
                    accx[o] = fmaf(A.x, w, accx[o]);
                    accy[o] = fmaf(A.y, w, accy[o]);
                    accz[o] = fmaf(A.z, w, accz[o]);
                    accw[o] += w;
                }
            }
        }
    }

    // ---- epilogue ----
    const int xo = x0 + tx;
    #pragma unroll
    for (int o = 0; o < RPT; ++o) {
        int y = y0 + ty * RPT + o;
        if (y < HH) {
            float inv = fast_rcp(accw[o]);
            size_t base = ((size_t)y * WW + xo) * 3;
            out[base + 0] = accx[o] * inv;
            out[base + 1] = accy[o] * inv;
            out[base + 2] = accz[o] * inv;
        }
    }
}

extern "C" void kernel_launch(void* const* d_in, const int* in_sizes, int n_in,
                              void* d_out, int out_size, void* d_ws, size_t ws_size,
                              hipStream_t stream) {
    const float* in = (const float*)d_in[0];
    float* out = (float*)d_out;
    dim3 grid((WW + TX - 1) / TX, (HH + TY - 1) / TY);   // 60 x 34
    dim3 block(TX, BDY);                                  // 256 threads
    hipLaunchKernelGGL(denoise_kernel, grid, block, 0, stream, in, out);
}